// Round 1
// baseline (170.325 us; speedup 1.0000x reference)
//
#include <hip/hip_runtime.h>
#include <hip/hip_bf16.h>

#define NPIX 4096
#define BATCH 4
#define CDIM 64
#define KDIM 8
#define CHDIM 32

typedef float f32x4 __attribute__((ext_vector_type(4)));
typedef short bf16x8 __attribute__((ext_vector_type(8)));

struct U2 { unsigned x, y; };

__device__ __forceinline__ unsigned short f2bf(float f) {
    union { float f; unsigned u; } v; v.f = f;
    unsigned r = v.u + 0x7FFF + ((v.u >> 16) & 1);   // RNE
    return (unsigned short)(r >> 16);
}

// ---------------------------------------------------------------------------
// Kernel 1: per-pixel projections f,g,h (1x1 convs), fp32 -> bf16, MFMA layouts
//   fB,gB: [b][n][8]      (per-pixel k-vector, 16B contiguous)
//   hBt:   [b][n/8][32][n%8]  (PV A-fragment tiled layout)
// ---------------------------------------------------------------------------
__global__ void proj_kernel(const float* __restrict__ x,
                            const float* __restrict__ Wf, const float* __restrict__ bf,
                            const float* __restrict__ Wg, const float* __restrict__ bg,
                            const float* __restrict__ Wh, const float* __restrict__ bh,
                            unsigned short* __restrict__ fB,
                            unsigned short* __restrict__ gB,
                            unsigned short* __restrict__ hBt) {
    __shared__ float wf[KDIM * CDIM], wg[KDIM * CDIM], wh[CHDIM * CDIM];
    __shared__ float bfs[KDIM], bgs[KDIM], bhs[CHDIM];
    for (int t = threadIdx.x; t < KDIM * CDIM; t += blockDim.x) { wf[t] = Wf[t]; wg[t] = Wg[t]; }
    for (int t = threadIdx.x; t < CHDIM * CDIM; t += blockDim.x) wh[t] = Wh[t];
    if (threadIdx.x < KDIM)  { bfs[threadIdx.x] = bf[threadIdx.x]; bgs[threadIdx.x] = bg[threadIdx.x]; }
    if (threadIdx.x < CHDIM) bhs[threadIdx.x] = bh[threadIdx.x];
    __syncthreads();

    int idx = blockIdx.x * blockDim.x + threadIdx.x;   // over BATCH*NPIX
    if (idx >= BATCH * NPIX) return;
    int b = idx / NPIX, n = idx % NPIX;
    const float* xb = x + (size_t)b * CDIM * NPIX + n;

    float facc[KDIM], gacc[KDIM], hacc[CHDIM];
#pragma unroll
    for (int k = 0; k < KDIM; k++) { facc[k] = bfs[k]; gacc[k] = bgs[k]; }
#pragma unroll
    for (int c = 0; c < CHDIM; c++) hacc[c] = bhs[c];

    for (int c = 0; c < CDIM; c++) {
        float xv = xb[(size_t)c * NPIX];
#pragma unroll
        for (int k = 0; k < KDIM; k++) { facc[k] += wf[k * CDIM + c] * xv; gacc[k] += wg[k * CDIM + c] * xv; }
#pragma unroll
        for (int ch = 0; ch < CHDIM; ch++) hacc[ch] += wh[ch * CDIM + c] * xv;
    }

    unsigned short* fo = fB + ((size_t)b * NPIX + n) * KDIM;
    unsigned short* go = gB + ((size_t)b * NPIX + n) * KDIM;
#pragma unroll
    for (int k = 0; k < KDIM; k++) { fo[k] = f2bf(facc[k]); go[k] = f2bf(gacc[k]); }

    int jc = n >> 3, t = n & 7;
    unsigned short* ho = hBt + ((size_t)b * (NPIX / 8) + jc) * (CHDIM * 8) + t;
#pragma unroll
    for (int ch = 0; ch < CHDIM; ch++) ho[ch * 8] = f2bf(hacc[ch]);
}

// ---------------------------------------------------------------------------
// Kernel 2: flash attention.  1 wave = 16 i-rows; loop over j in tiles of 32.
//   S^T tile = mfma(A=g, B=f): D lane layout col=i=lane&15, row=j=(lane>>4)*4+reg
//   online softmax (m,l per i-row; row-reduce = 2x shfl_xor)
//   P -> bf16 via per-wave LDS roundtrip -> B-frag of PV
//   O^T[c][i] += mfma(A=h, B=P^T), 2 c-tiles
// ---------------------------------------------------------------------------
__global__ __launch_bounds__(256) void attn_kernel(const unsigned short* __restrict__ fB,
                                                   const unsigned short* __restrict__ gB,
                                                   const unsigned short* __restrict__ hBt,
                                                   float* __restrict__ oT) {
    __shared__ unsigned short plds[4][16][32];   // per-wave P tile [i][j], bf16

    const int wid = threadIdx.x >> 6;
    const int lane = threadIdx.x & 63;
    const int li = lane & 15;
    const int q = lane >> 4;
    const int b = blockIdx.y;
    const int i0 = blockIdx.x * 64 + wid * 16;

    bf16x8 ffrag = {};
    if (lane < 16)
        ffrag = *(const bf16x8*)(fB + ((size_t)b * NPIX + i0 + lane) * KDIM);

    f32x4 acc0 = {0.f, 0.f, 0.f, 0.f};
    f32x4 acc1 = {0.f, 0.f, 0.f, 0.f};
    float m = -1e30f, l = 0.f;
    const float L2E = 1.44269504088896f;

    for (int jb = 0; jb < NPIX; jb += 32) {
        bf16x8 g0 = {}, g1 = {};
        if (lane < 16) {
            g0 = *(const bf16x8*)(gB + ((size_t)b * NPIX + jb + lane) * KDIM);
            g1 = *(const bf16x8*)(gB + ((size_t)b * NPIX + jb + 16 + lane) * KDIM);
        }
        // h A-fragments (independent of softmax -> can be prefetched by compiler)
        const unsigned short* hbase = hBt + ((size_t)b * (NPIX / 8) + (jb >> 3) + q) * (CHDIM * 8);
        bf16x8 h0 = *(const bf16x8*)(hbase + li * 8);
        bf16x8 h1 = *(const bf16x8*)(hbase + (16 + li) * 8);

        f32x4 z = {0.f, 0.f, 0.f, 0.f};
        f32x4 st0 = __builtin_amdgcn_mfma_f32_16x16x32_bf16(g0, ffrag, z, 0, 0, 0);
        f32x4 st1 = __builtin_amdgcn_mfma_f32_16x16x32_bf16(g1, ffrag, z, 0, 0, 0);
        // lane holds S^T[j][i]: i = li; st0: j = jb+4q+r, st1: j = jb+16+4q+r

        float tmax = fmaxf(fmaxf(fmaxf(st0[0], st0[1]), fmaxf(st0[2], st0[3])),
                           fmaxf(fmaxf(st1[0], st1[1]), fmaxf(st1[2], st1[3])));
        tmax = fmaxf(tmax, __shfl_xor(tmax, 16));
        tmax = fmaxf(tmax, __shfl_xor(tmax, 32));

        float mn = fmaxf(m, tmax);
        float scale = exp2f((m - mn) * L2E);

        float p0 = exp2f((st0[0] - mn) * L2E);
        float p1 = exp2f((st0[1] - mn) * L2E);
        float p2 = exp2f((st0[2] - mn) * L2E);
        float p3 = exp2f((st0[3] - mn) * L2E);
        float p4 = exp2f((st1[0] - mn) * L2E);
        float p5 = exp2f((st1[1] - mn) * L2E);
        float p6 = exp2f((st1[2] - mn) * L2E);
        float p7 = exp2f((st1[3] - mn) * L2E);

        float ts = ((p0 + p1) + (p2 + p3)) + ((p4 + p5) + (p6 + p7));
        ts += __shfl_xor(ts, 16);
        ts += __shfl_xor(ts, 32);

        l = l * scale + ts;
        m = mn;
        acc0 *= scale;
        acc1 *= scale;

        // pack P to bf16, roundtrip through per-wave LDS to get PV B-fragment
        unsigned u01 = (unsigned)f2bf(p0) | ((unsigned)f2bf(p1) << 16);
        unsigned u23 = (unsigned)f2bf(p2) | ((unsigned)f2bf(p3) << 16);
        unsigned u45 = (unsigned)f2bf(p4) | ((unsigned)f2bf(p5) << 16);
        unsigned u67 = (unsigned)f2bf(p6) | ((unsigned)f2bf(p7) << 16);
        *(U2*)&plds[wid][li][4 * q]      = U2{u01, u23};
        *(U2*)&plds[wid][li][16 + 4 * q] = U2{u45, u67};

        bf16x8 pfrag = *(const bf16x8*)&plds[wid][li][8 * q];

        acc0 = __builtin_amdgcn_mfma_f32_16x16x32_bf16(h0, pfrag, acc0, 0, 0, 0);
        acc1 = __builtin_amdgcn_mfma_f32_16x16x32_bf16(h1, pfrag, acc1, 0, 0, 0);
    }

    // epilogue: O^T[c][i] / l  -> oT [b][32][N] fp32
    float invl = 1.0f / l;
    float* ob = oT + (size_t)b * CHDIM * NPIX + (i0 + li);
#pragma unroll
    for (int r = 0; r < 4; r++) {
        int c0 = q * 4 + r;
        ob[(size_t)c0 * NPIX]        = acc0[r] * invl;
        ob[(size_t)(16 + c0) * NPIX] = acc1[r] * invl;
    }
}

// ---------------------------------------------------------------------------
// Kernel 3: out = gamma * (Wv @ o + bv) + x
// ---------------------------------------------------------------------------
__global__ void out_kernel(const float* __restrict__ oT, const float* __restrict__ x,
                           const float* __restrict__ Wv, const float* __restrict__ bv,
                           const float* __restrict__ gamma, float* __restrict__ out) {
    __shared__ float wv[CDIM * CHDIM];
    __shared__ float bvs[CDIM];
    for (int t = threadIdx.x; t < CDIM * CHDIM; t += blockDim.x) wv[t] = Wv[t];
    if (threadIdx.x < CDIM) bvs[threadIdx.x] = bv[threadIdx.x];
    __syncthreads();

    float gm = gamma[0];
    int idx = blockIdx.x * blockDim.x + threadIdx.x;
    if (idx >= BATCH * NPIX) return;
    int b = idx / NPIX, n = idx % NPIX;

    const float* ob = oT + (size_t)b * CHDIM * NPIX + n;
    float ov[CHDIM];
#pragma unroll
    for (int ch = 0; ch < CHDIM; ch++) ov[ch] = ob[(size_t)ch * NPIX];

    const float* xb = x + (size_t)b * CDIM * NPIX + n;
    float* yb = out + (size_t)b * CDIM * NPIX + n;
    for (int c = 0; c < CDIM; c++) {
        float acc = bvs[c];
#pragma unroll
        for (int ch = 0; ch < CHDIM; ch++) acc += wv[c * CHDIM + ch] * ov[ch];
        yb[(size_t)c * NPIX] = gm * acc + xb[(size_t)c * NPIX];
    }
}

extern "C" void kernel_launch(void* const* d_in, const int* in_sizes, int n_in,
                              void* d_out, int out_size, void* d_ws, size_t ws_size,
                              hipStream_t stream) {
    const float* x     = (const float*)d_in[0];
    const float* Wf    = (const float*)d_in[1];
    const float* bf    = (const float*)d_in[2];
    const float* Wg    = (const float*)d_in[3];
    const float* bg    = (const float*)d_in[4];
    const float* Wh    = (const float*)d_in[5];
    const float* bh    = (const float*)d_in[6];
    const float* Wv    = (const float*)d_in[7];
    const float* bv    = (const float*)d_in[8];
    const float* gamma = (const float*)d_in[9];
    float* out = (float*)d_out;

    unsigned short* fBp = (unsigned short*)d_ws;                    // 4*4096*8 bf16
    unsigned short* gBp = fBp + (size_t)BATCH * NPIX * KDIM;        // 4*4096*8
    unsigned short* hBt = gBp + (size_t)BATCH * NPIX * KDIM;        // 4*4096*32
    float* oT = (float*)(hBt + (size_t)BATCH * NPIX * CHDIM);       // 4*32*4096 f32

    hipLaunchKernelGGL(proj_kernel, dim3((BATCH * NPIX) / 256), dim3(256), 0, stream,
                       x, Wf, bf, Wg, bg, Wh, bh, fBp, gBp, hBt);
    hipLaunchKernelGGL(attn_kernel, dim3(NPIX / 64, BATCH), dim3(256), 0, stream,
                       fBp, gBp, hBt, oT);
    hipLaunchKernelGGL(out_kernel, dim3((BATCH * NPIX) / 256), dim3(256), 0, stream,
                       oT, x, Wv, bv, gamma, out);
}

// Round 2
// 56.831 us; speedup vs baseline: 2.9970x; 2.9970x over previous
//
#include <hip/hip_runtime.h>
#include <hip/hip_bf16.h>

#define NPIX 4096
#define BATCH 4
#define CDIM 64
#define KDIM 8
#define CHDIM 32

typedef float f32x4 __attribute__((ext_vector_type(4)));
typedef short bf16x8 __attribute__((ext_vector_type(8)));

struct U2 { unsigned x, y; };

__device__ __forceinline__ unsigned short f2bf(float f) {
    union { float f; unsigned u; } v; v.f = f;
    unsigned r = v.u + 0x7FFF + ((v.u >> 16) & 1);   // RNE
    return (unsigned short)(r >> 16);
}

__device__ __forceinline__ float fast_exp2(float x) {
#if __has_builtin(__builtin_amdgcn_exp2f)
    return __builtin_amdgcn_exp2f(x);
#else
    return exp2f(x);
#endif
}

// ---------------------------------------------------------------------------
// Kernel 1: projections. 2 thread-groups per pixel (og=0: f,g,h[0:8];
// og=1: h[8:32]) selected by block so branches are wave-uniform.
// f is pre-scaled by log2(e) so attn can exp2 raw MFMA output.
//   fB,gB: [b][n][8] bf16;  hBt: [b][n/8][32][n%8] bf16 (PV A-frag layout)
// ---------------------------------------------------------------------------
__global__ __launch_bounds__(128) void proj_kernel(
        const float* __restrict__ x,
        const float* __restrict__ Wf, const float* __restrict__ bf,
        const float* __restrict__ Wg, const float* __restrict__ bg,
        const float* __restrict__ Wh, const float* __restrict__ bh,
        unsigned short* __restrict__ fB,
        unsigned short* __restrict__ gB,
        unsigned short* __restrict__ hBt) {
    __shared__ float wf[KDIM * CDIM], wg[KDIM * CDIM], wh[CHDIM * CDIM];
    __shared__ float bfs[KDIM], bgs[KDIM], bhs[CHDIM];
    for (int t = threadIdx.x; t < KDIM * CDIM; t += 128) { wf[t] = Wf[t]; wg[t] = Wg[t]; }
    for (int t = threadIdx.x; t < CHDIM * CDIM; t += 128) wh[t] = Wh[t];
    if (threadIdx.x < KDIM)  { bfs[threadIdx.x] = bf[threadIdx.x]; bgs[threadIdx.x] = bg[threadIdx.x]; }
    if (threadIdx.x < CHDIM) bhs[threadIdx.x] = bh[threadIdx.x];
    __syncthreads();

    const float L2E = 1.44269504088896f;
    int pix = (blockIdx.x & 127) * 128 + threadIdx.x;   // 0..16383
    int og  = blockIdx.x >> 7;                          // wave-uniform
    int b = pix >> 12, n = pix & (NPIX - 1);
    const float* xb = x + (size_t)b * CDIM * NPIX + n;
    unsigned short* ho = hBt + ((size_t)b * (NPIX / 8) + (n >> 3)) * (CHDIM * 8) + (n & 7);

    if (og == 0) {
        float acc[24];
#pragma unroll
        for (int k = 0; k < KDIM; k++) { acc[k] = bfs[k]; acc[8 + k] = bgs[k]; acc[16 + k] = bhs[k]; }
        for (int c = 0; c < CDIM; c++) {
            float xv = xb[(size_t)c * NPIX];
#pragma unroll
            for (int k = 0; k < KDIM; k++) {
                acc[k]      += wf[k * CDIM + c] * xv;
                acc[8 + k]  += wg[k * CDIM + c] * xv;
                acc[16 + k] += wh[k * CDIM + c] * xv;
            }
        }
        unsigned short* fo = fB + (size_t)pix * KDIM;
        unsigned short* go = gB + (size_t)pix * KDIM;
#pragma unroll
        for (int k = 0; k < KDIM; k++) {
            fo[k] = f2bf(acc[k] * L2E);          // fold log2(e) into f
            go[k] = f2bf(acc[8 + k]);
            ho[k * 8] = f2bf(acc[16 + k]);
        }
    } else {
        float acc[24];
#pragma unroll
        for (int k = 0; k < 24; k++) acc[k] = bhs[8 + k];
        for (int c = 0; c < CDIM; c++) {
            float xv = xb[(size_t)c * NPIX];
#pragma unroll
            for (int k = 0; k < 24; k++) acc[k] += wh[(8 + k) * CDIM + c] * xv;
        }
#pragma unroll
        for (int k = 0; k < 24; k++) ho[(8 + k) * 8] = f2bf(acc[k]);
    }
}

// ---------------------------------------------------------------------------
// Kernel 2: flash attention, j-split for occupancy, no max-tracking.
//   wave = 16 i-rows, j-chunk = jlen per block (grid.z splits).
//   S^T = mfma(g, f) -> p = exp2(st) -> pack (cvt_pk) -> padded-LDS roundtrip
//   -> O^T += mfma(h, P);  partial acc + partial l written to ws.
// ---------------------------------------------------------------------------
__global__ __launch_bounds__(256) void attn_kernel(
        const unsigned short* __restrict__ fB,
        const unsigned short* __restrict__ gB,
        const unsigned short* __restrict__ hBt,
        float* __restrict__ oTp, float* __restrict__ lp, int jlen) {
    __shared__ unsigned short plds[4][16][40];   // padded: 80B rows (16B-aligned)

    const int wid = threadIdx.x >> 6;
    const int lane = threadIdx.x & 63;
    const int li = lane & 15;
    const int q = lane >> 4;
    const int b = blockIdx.y;
    const int split = blockIdx.z;
    const int i0 = blockIdx.x * 64 + wid * 16;
    const int j0 = split * jlen;

    bf16x8 ffrag = {};
    if (lane < 16)
        ffrag = *(const bf16x8*)(fB + ((size_t)b * NPIX + i0 + lane) * KDIM);

    f32x4 acc0 = {0.f, 0.f, 0.f, 0.f};
    f32x4 acc1 = {0.f, 0.f, 0.f, 0.f};
    float lsum = 0.f;

    const unsigned short* gb = gB + ((size_t)b * NPIX + j0 + lane) * KDIM;
    const unsigned short* hb = hBt + ((size_t)b * (NPIX / 8) + (j0 >> 3) + q) * (CHDIM * 8) + li * 8;

    for (int jb = 0; jb < jlen; jb += 32) {
        bf16x8 g0 = {}, g1 = {};
        if (lane < 16) {
            g0 = *(const bf16x8*)(gb);
            g1 = *(const bf16x8*)(gb + 16 * KDIM);
        }
        bf16x8 h0 = *(const bf16x8*)(hb);          // ch = li,    k = 8q+e
        bf16x8 h1 = *(const bf16x8*)(hb + 128);    // ch = 16+li, k = 8q+e

        f32x4 z = {0.f, 0.f, 0.f, 0.f};
        f32x4 st0 = __builtin_amdgcn_mfma_f32_16x16x32_bf16(g0, ffrag, z, 0, 0, 0);
        f32x4 st1 = __builtin_amdgcn_mfma_f32_16x16x32_bf16(g1, ffrag, z, 0, 0, 0);
        // lane holds S^T*log2e at i=li; st0: j=jb+4q+r, st1: j=jb+16+4q+r

        float p0 = fast_exp2(st0[0]), p1 = fast_exp2(st0[1]);
        float p2 = fast_exp2(st0[2]), p3 = fast_exp2(st0[3]);
        float p4 = fast_exp2(st1[0]), p5 = fast_exp2(st1[1]);
        float p6 = fast_exp2(st1[2]), p7 = fast_exp2(st1[3]);

        lsum += ((p0 + p1) + (p2 + p3)) + ((p4 + p5) + (p6 + p7));

        unsigned u01, u23, u45, u67;
        asm("v_cvt_pk_bf16_f32 %0, %1, %2" : "=v"(u01) : "v"(p0), "v"(p1));
        asm("v_cvt_pk_bf16_f32 %0, %1, %2" : "=v"(u23) : "v"(p2), "v"(p3));
        asm("v_cvt_pk_bf16_f32 %0, %1, %2" : "=v"(u45) : "v"(p4), "v"(p5));
        asm("v_cvt_pk_bf16_f32 %0, %1, %2" : "=v"(u67) : "v"(p6), "v"(p7));
        *(U2*)&plds[wid][li][4 * q]      = U2{u01, u23};
        *(U2*)&plds[wid][li][16 + 4 * q] = U2{u45, u67};

        bf16x8 pfrag = *(const bf16x8*)&plds[wid][li][8 * q];

        acc0 = __builtin_amdgcn_mfma_f32_16x16x32_bf16(h0, pfrag, acc0, 0, 0, 0);
        acc1 = __builtin_amdgcn_mfma_f32_16x16x32_bf16(h1, pfrag, acc1, 0, 0, 0);

        gb += 32 * KDIM;
        hb += 4 * CHDIM * 8;
    }

    // reduce l across the 4 q-groups (per i-row)
    lsum += __shfl_xor(lsum, 16);
    lsum += __shfl_xor(lsum, 32);

    float* ob = oTp + ((size_t)(split * BATCH + b) * CHDIM) * NPIX + (i0 + li);
#pragma unroll
    for (int r = 0; r < 4; r++) {
        int c0 = q * 4 + r;
        ob[(size_t)c0 * NPIX]        = acc0[r];
        ob[(size_t)(16 + c0) * NPIX] = acc1[r];
    }
    if (lane < 16)
        lp[(size_t)(split * BATCH + b) * NPIX + i0 + lane] = lsum;
}

// ---------------------------------------------------------------------------
// Kernel 3: merge splits (plain sum — no max tracking) + Wv + residual.
// Block = 64 pixels; oT tile staged in LDS.
// ---------------------------------------------------------------------------
__global__ __launch_bounds__(256) void out_kernel(
        const float* __restrict__ oTp, const float* __restrict__ lp,
        const float* __restrict__ x,
        const float* __restrict__ Wv, const float* __restrict__ bv,
        const float* __restrict__ gamma, float* __restrict__ out, int nsplit) {
    __shared__ float wv[CDIM * CHDIM];
    __shared__ float bvs[CDIM];
    __shared__ float otile[CHDIM * 64];
    __shared__ float linv[64];

    int t = threadIdx.x;
    for (int i = t; i < CDIM * CHDIM; i += 256) wv[i] = Wv[i];
    if (t < CDIM) bvs[t] = bv[t];

    int n0 = blockIdx.x * 64, b = blockIdx.y;

    float racc[8] = {0.f, 0.f, 0.f, 0.f, 0.f, 0.f, 0.f, 0.f};
    for (int s = 0; s < nsplit; s++) {
        const float* base = oTp + ((size_t)(s * BATCH + b) * CHDIM) * NPIX + n0;
#pragma unroll
        for (int r = 0; r < 8; r++) {
            int e = t + r * 256;
            racc[r] += base[(size_t)(e >> 6) * NPIX + (e & 63)];
        }
    }
#pragma unroll
    for (int r = 0; r < 8; r++) otile[t + r * 256] = racc[r];

    if (t < 64) {
        float ls = 0.f;
        for (int s = 0; s < nsplit; s++)
            ls += lp[(size_t)(s * BATCH + b) * NPIX + n0 + t];
        linv[t] = 1.0f / ls;
    }
    __syncthreads();

    int px = t & 63, cq = t >> 6;
    float invl = linv[px];
    float gm = gamma[0];
    for (int cc = 0; cc < 16; cc++) {
        int c = cq * 16 + cc;
        float a = 0.f;
#pragma unroll
        for (int ch = 0; ch < CHDIM; ch++) a += wv[c * CHDIM + ch] * otile[ch * 64 + px];
        size_t o = ((size_t)b * CDIM + c) * NPIX + n0 + px;
        out[o] = gm * (a * invl + bvs[c]) + x[o];
    }
}

extern "C" void kernel_launch(void* const* d_in, const int* in_sizes, int n_in,
                              void* d_out, int out_size, void* d_ws, size_t ws_size,
                              hipStream_t stream) {
    const float* x     = (const float*)d_in[0];
    const float* Wf    = (const float*)d_in[1];
    const float* bf    = (const float*)d_in[2];
    const float* Wg    = (const float*)d_in[3];
    const float* bg    = (const float*)d_in[4];
    const float* Wh    = (const float*)d_in[5];
    const float* bh    = (const float*)d_in[6];
    const float* Wv    = (const float*)d_in[7];
    const float* bv    = (const float*)d_in[8];
    const float* gamma = (const float*)d_in[9];
    float* out = (float*)d_out;

    unsigned short* fBp = (unsigned short*)d_ws;                    // 4*4096*8 bf16
    unsigned short* gBp = fBp + (size_t)BATCH * NPIX * KDIM;        // 4*4096*8
    unsigned short* hBt = gBp + (size_t)BATCH * NPIX * KDIM;        // 4*4096*32
    float* oTp = (float*)(hBt + (size_t)BATCH * NPIX * CHDIM);

    // choose split count from available scratch: fixed 1.5MB + nsplit*2.16MB
    size_t fixedB   = (size_t)BATCH * NPIX * (KDIM * 2 * 2 + CHDIM * 2);
    size_t perSplit = (size_t)BATCH * CHDIM * NPIX * 4 + (size_t)BATCH * NPIX * 4;
    int nsplit = 1;
    while (nsplit < 8 && fixedB + (size_t)(nsplit * 2) * perSplit <= ws_size) nsplit *= 2;
    int jlen = NPIX / nsplit;

    float* lp = oTp + (size_t)nsplit * BATCH * CHDIM * NPIX;

    hipLaunchKernelGGL(proj_kernel, dim3(256), dim3(128), 0, stream,
                       x, Wf, bf, Wg, bg, Wh, bh, fBp, gBp, hBt);
    hipLaunchKernelGGL(attn_kernel, dim3(NPIX / 64, BATCH, nsplit), dim3(256), 0, stream,
                       fBp, gBp, hBt, oTp, lp, jlen);
    hipLaunchKernelGGL(out_kernel, dim3(NPIX / 64, BATCH), dim3(256), 0, stream,
                       oTp, lp, x, Wv, bv, gamma, out, nsplit);
}

// Round 3
// 46.938 us; speedup vs baseline: 3.6287x; 1.2108x over previous
//
#include <hip/hip_runtime.h>
#include <hip/hip_bf16.h>

#define NPIX 4096
#define BATCH 4
#define CDIM 64
#define KDIM 8
#define CHDIM 32

typedef float f32x4 __attribute__((ext_vector_type(4)));
typedef short bf16x8 __attribute__((ext_vector_type(8)));

struct U2 { unsigned x, y; };

__device__ __forceinline__ unsigned short f2bf(float f) {
    union { float f; unsigned u; } v; v.f = f;
    unsigned r = v.u + 0x7FFF + ((v.u >> 16) & 1);   // RNE
    return (unsigned short)(r >> 16);
}

__device__ __forceinline__ float bf2f(unsigned short u) {
    union { unsigned u; float f; } v; v.u = ((unsigned)u) << 16;
    return v.f;
}

__device__ __forceinline__ float fast_exp2(float x) {
#if __has_builtin(__builtin_amdgcn_exp2f)
    return __builtin_amdgcn_exp2f(x);
#else
    return exp2f(x);
#endif
}

// ---------------------------------------------------------------------------
// Kernel 1: projections as 3 output-groups x 2 c-halves.
//   og=0: f[0:8]+g[0:8], og=1: h[0:16), og=2: h[16:32).
//   Weights read via wave-uniform scalar loads (no LDS) -> v_fmac w/ SGPR.
//   c-halves reduced through LDS. f pre-scaled by log2(e).
//   fB,gB: [b][n][8] bf16;  hBt: [b][n/8][32][n%8] bf16 (PV A-frag layout)
// ---------------------------------------------------------------------------
__global__ __launch_bounds__(256) void proj_kernel(
        const float* __restrict__ x,
        const float* __restrict__ Wf, const float* __restrict__ bf,
        const float* __restrict__ Wg, const float* __restrict__ bg,
        const float* __restrict__ Wh, const float* __restrict__ bh,
        unsigned short* __restrict__ fB,
        unsigned short* __restrict__ gB,
        unsigned short* __restrict__ hBt) {
    __shared__ float red[16][128];

    const int t = threadIdx.x;
    const int px = t & 127;
    const int ch = __builtin_amdgcn_readfirstlane(t >> 7);   // wave-uniform 0/1
    const int og = blockIdx.y;                                // uniform 0..2
    const int pix = blockIdx.x * 128 + px;
    const int b = pix >> 12, n = pix & (NPIX - 1);
    const float L2E = 1.44269504088896f;

    // load this c-half of x column into registers (coalesced across lanes)
    const float* xb = x + (size_t)b * CDIM * NPIX + n + (size_t)(ch * 32) * NPIX;
    float xv[32];
#pragma unroll 8
    for (int c = 0; c < 32; c++) xv[c] = xb[(size_t)c * NPIX];

    float acc[16];

    if (og == 0) {
        const float* wf = Wf + ch * 32;
        const float* wg = Wg + ch * 32;
#pragma unroll
        for (int r = 0; r < 8; r++) {
            acc[r]     = ch ? 0.f : bf[r];
            acc[8 + r] = ch ? 0.f : bg[r];
        }
#pragma unroll 4
        for (int c = 0; c < 32; c++) {
            float v = xv[c];
#pragma unroll
            for (int r = 0; r < 8; r++) {
                acc[r]     += wf[r * CDIM + c] * v;
                acc[8 + r] += wg[r * CDIM + c] * v;
            }
        }
    } else if (og == 1) {
        const float* wh = Wh + ch * 32;
#pragma unroll
        for (int r = 0; r < 16; r++) acc[r] = ch ? 0.f : bh[r];
#pragma unroll 4
        for (int c = 0; c < 32; c++) {
            float v = xv[c];
#pragma unroll
            for (int r = 0; r < 16; r++) acc[r] += wh[r * CDIM + c] * v;
        }
    } else {
        const float* wh = Wh + 16 * CDIM + ch * 32;
#pragma unroll
        for (int r = 0; r < 16; r++) acc[r] = ch ? 0.f : bh[16 + r];
#pragma unroll 4
        for (int c = 0; c < 32; c++) {
            float v = xv[c];
#pragma unroll
            for (int r = 0; r < 16; r++) acc[r] += wh[r * CDIM + c] * v;
        }
    }

    if (ch) {
#pragma unroll
        for (int r = 0; r < 16; r++) red[r][px] = acc[r];
    }
    __syncthreads();
    if (!ch) {
#pragma unroll
        for (int r = 0; r < 16; r++) acc[r] += red[r][px];

        unsigned short* ho = hBt + ((size_t)b * (NPIX / 8) + (n >> 3)) * (CHDIM * 8) + (n & 7);
        if (og == 0) {
            unsigned short* fo = fB + (size_t)pix * KDIM;
            unsigned short* go = gB + (size_t)pix * KDIM;
#pragma unroll
            for (int r = 0; r < 8; r++) {
                fo[r] = f2bf(acc[r] * L2E);      // fold log2(e) into f
                go[r] = f2bf(acc[8 + r]);
            }
        } else if (og == 1) {
#pragma unroll
            for (int r = 0; r < 16; r++) ho[r * 8] = f2bf(acc[r]);
        } else {
#pragma unroll
            for (int r = 0; r < 16; r++) ho[(16 + r) * 8] = f2bf(acc[r]);
        }
    }
}

// ---------------------------------------------------------------------------
// Kernel 2: flash attention, j-split for occupancy, no max-tracking.
//   wave = 16 i-rows, j-chunk = jlen per block (grid.z splits).
//   S^T = mfma(g, f) -> p = exp2(st) -> pack (cvt_pk) -> padded-LDS roundtrip
//   -> O^T += mfma(h, P);  bf16 partial acc + fp32 partial l to ws.
// ---------------------------------------------------------------------------
__global__ __launch_bounds__(256) void attn_kernel(
        const unsigned short* __restrict__ fB,
        const unsigned short* __restrict__ gB,
        const unsigned short* __restrict__ hBt,
        unsigned short* __restrict__ oTp, float* __restrict__ lp, int jlen) {
    __shared__ unsigned short plds[4][16][40];   // padded rows: 80B, 16B-aligned

    const int wid = threadIdx.x >> 6;
    const int lane = threadIdx.x & 63;
    const int li = lane & 15;
    const int q = lane >> 4;
    const int b = blockIdx.y;
    const int split = blockIdx.z;
    const int i0 = blockIdx.x * 64 + wid * 16;
    const int j0 = split * jlen;

    bf16x8 ffrag = {};
    if (lane < 16)
        ffrag = *(const bf16x8*)(fB + ((size_t)b * NPIX + i0 + lane) * KDIM);

    f32x4 acc0 = {0.f, 0.f, 0.f, 0.f};
    f32x4 acc1 = {0.f, 0.f, 0.f, 0.f};
    float lsum = 0.f;

    const unsigned short* gb = gB + ((size_t)b * NPIX + j0 + lane) * KDIM;
    const unsigned short* hb = hBt + ((size_t)b * (NPIX / 8) + (j0 >> 3) + q) * (CHDIM * 8) + li * 8;

    for (int jb = 0; jb < jlen; jb += 32) {
        bf16x8 g0 = {}, g1 = {};
        if (lane < 16) {
            g0 = *(const bf16x8*)(gb);
            g1 = *(const bf16x8*)(gb + 16 * KDIM);
        }
        bf16x8 h0 = *(const bf16x8*)(hb);          // ch = li,    k = 8q+e
        bf16x8 h1 = *(const bf16x8*)(hb + 128);    // ch = 16+li, k = 8q+e

        f32x4 z = {0.f, 0.f, 0.f, 0.f};
        f32x4 st0 = __builtin_amdgcn_mfma_f32_16x16x32_bf16(g0, ffrag, z, 0, 0, 0);
        f32x4 st1 = __builtin_amdgcn_mfma_f32_16x16x32_bf16(g1, ffrag, z, 0, 0, 0);
        // lane holds S^T*log2e at i=li; st0: j=jb+4q+r, st1: j=jb+16+4q+r

        float p0 = fast_exp2(st0[0]), p1 = fast_exp2(st0[1]);
        float p2 = fast_exp2(st0[2]), p3 = fast_exp2(st0[3]);
        float p4 = fast_exp2(st1[0]), p5 = fast_exp2(st1[1]);
        float p6 = fast_exp2(st1[2]), p7 = fast_exp2(st1[3]);

        lsum += ((p0 + p1) + (p2 + p3)) + ((p4 + p5) + (p6 + p7));

        unsigned u01, u23, u45, u67;
        asm("v_cvt_pk_bf16_f32 %0, %1, %2" : "=v"(u01) : "v"(p0), "v"(p1));
        asm("v_cvt_pk_bf16_f32 %0, %1, %2" : "=v"(u23) : "v"(p2), "v"(p3));
        asm("v_cvt_pk_bf16_f32 %0, %1, %2" : "=v"(u45) : "v"(p4), "v"(p5));
        asm("v_cvt_pk_bf16_f32 %0, %1, %2" : "=v"(u67) : "v"(p6), "v"(p7));
        *(U2*)&plds[wid][li][4 * q]      = U2{u01, u23};
        *(U2*)&plds[wid][li][16 + 4 * q] = U2{u45, u67};

        bf16x8 pfrag = *(const bf16x8*)&plds[wid][li][8 * q];

        acc0 = __builtin_amdgcn_mfma_f32_16x16x32_bf16(h0, pfrag, acc0, 0, 0, 0);
        acc1 = __builtin_amdgcn_mfma_f32_16x16x32_bf16(h1, pfrag, acc1, 0, 0, 0);

        gb += 32 * KDIM;
        hb += 4 * CHDIM * 8;
    }

    // reduce l across the 4 q-groups (per i-row)
    lsum += __shfl_xor(lsum, 16);
    lsum += __shfl_xor(lsum, 32);

    unsigned short* ob = oTp + ((size_t)(split * BATCH + b) * CHDIM) * NPIX + (i0 + li);
#pragma unroll
    for (int r = 0; r < 4; r++) {
        int c0 = q * 4 + r;
        ob[(size_t)c0 * NPIX]        = f2bf(acc0[r]);
        ob[(size_t)(16 + c0) * NPIX] = f2bf(acc1[r]);
    }
    if (lane < 16)
        lp[(size_t)(split * BATCH + b) * NPIX + i0 + lane] = lsum;
}

// ---------------------------------------------------------------------------
// Kernel 3: merge bf16 splits (plain sum) + Wv (SGPR weights) + residual.
// Block = 64 pixels x 4 c-quarters; merged oT tile staged in LDS.
// ---------------------------------------------------------------------------
__global__ __launch_bounds__(256) void out_kernel(
        const unsigned short* __restrict__ oTp, const float* __restrict__ lp,
        const float* __restrict__ x,
        const float* __restrict__ Wv, const float* __restrict__ bv,
        const float* __restrict__ gamma, float* __restrict__ out, int nsplit) {
    __shared__ float otile[CHDIM * 64];
    __shared__ float linv[64];

    const int t = threadIdx.x;
    const int n0 = blockIdx.x * 64, b = blockIdx.y;

    float racc[8] = {0.f, 0.f, 0.f, 0.f, 0.f, 0.f, 0.f, 0.f};
    for (int s = 0; s < nsplit; s++) {
        const unsigned short* base = oTp + ((size_t)(s * BATCH + b) * CHDIM) * NPIX + n0;
#pragma unroll
        for (int r = 0; r < 8; r++) {
            int e = t + r * 256;
            racc[r] += bf2f(base[(size_t)(e >> 6) * NPIX + (e & 63)]);
        }
    }
#pragma unroll
    for (int r = 0; r < 8; r++) otile[t + r * 256] = racc[r];

    if (t < 64) {
        float ls = 0.f;
        for (int s = 0; s < nsplit; s++)
            ls += lp[(size_t)(s * BATCH + b) * NPIX + n0 + t];
        linv[t] = 1.0f / ls;
    }
    __syncthreads();

    const int px = t & 63;
    const int cq = __builtin_amdgcn_readfirstlane(t >> 6);   // wave-uniform
    float ov[CHDIM];
#pragma unroll
    for (int chh = 0; chh < CHDIM; chh++) ov[chh] = otile[chh * 64 + px];
    float invl = linv[px];
    float gm = gamma[0];

    const float* wq = Wv + cq * 16 * CHDIM;
#pragma unroll 4
    for (int cc = 0; cc < 16; cc++) {
        float a = 0.f;
#pragma unroll
        for (int chh = 0; chh < CHDIM; chh++) a += wq[cc * CHDIM + chh] * ov[chh];
        int c = cq * 16 + cc;
        size_t o = ((size_t)b * CDIM + c) * NPIX + n0 + px;
        out[o] = gm * (a * invl + bv[c]) + x[o];
    }
}

extern "C" void kernel_launch(void* const* d_in, const int* in_sizes, int n_in,
                              void* d_out, int out_size, void* d_ws, size_t ws_size,
                              hipStream_t stream) {
    const float* x     = (const float*)d_in[0];
    const float* Wf    = (const float*)d_in[1];
    const float* bf    = (const float*)d_in[2];
    const float* Wg    = (const float*)d_in[3];
    const float* bg    = (const float*)d_in[4];
    const float* Wh    = (const float*)d_in[5];
    const float* bh    = (const float*)d_in[6];
    const float* Wv    = (const float*)d_in[7];
    const float* bv    = (const float*)d_in[8];
    const float* gamma = (const float*)d_in[9];
    float* out = (float*)d_out;

    unsigned short* fBp = (unsigned short*)d_ws;                    // 4*4096*8 bf16
    unsigned short* gBp = fBp + (size_t)BATCH * NPIX * KDIM;        // 4*4096*8
    unsigned short* hBt = gBp + (size_t)BATCH * NPIX * KDIM;        // 4*4096*32
    unsigned short* oTp = hBt + (size_t)BATCH * NPIX * CHDIM;       // nsplit*4*32*4096 bf16

    // split count from scratch: fixed ~1.5MB + nsplit*(1MB + 64KB)
    size_t fixedB   = (size_t)BATCH * NPIX * (KDIM * 2 * 2 + CHDIM * 2);
    size_t perSplit = (size_t)BATCH * CHDIM * NPIX * 2 + (size_t)BATCH * NPIX * 4;
    int nsplit = 1;
    while (nsplit < 8 && fixedB + (size_t)(nsplit * 2) * perSplit <= ws_size) nsplit *= 2;
    int jlen = NPIX / nsplit;

    float* lp = (float*)(oTp + (size_t)nsplit * BATCH * CHDIM * NPIX);

    hipLaunchKernelGGL(proj_kernel, dim3(NPIX * BATCH / 128, 3), dim3(256), 0, stream,
                       x, Wf, bf, Wg, bg, Wh, bh, fBp, gBp, hBt);
    hipLaunchKernelGGL(attn_kernel, dim3(NPIX / 64, BATCH, nsplit), dim3(256), 0, stream,
                       fBp, gBp, hBt, oTp, lp, jlen);
    hipLaunchKernelGGL(out_kernel, dim3(NPIX / 64, BATCH), dim3(256), 0, stream,
                       oTp, lp, x, Wv, bv, gamma, out, nsplit);
}

// Round 4
// 44.826 us; speedup vs baseline: 3.7997x; 1.0471x over previous
//
#include <hip/hip_runtime.h>
#include <hip/hip_bf16.h>

#define NPIX 4096
#define BATCH 4
#define CDIM 64
#define KDIM 8
#define CHDIM 32

typedef float f32x4 __attribute__((ext_vector_type(4)));
typedef short bf16x8 __attribute__((ext_vector_type(8)));
typedef unsigned short ushort4v __attribute__((ext_vector_type(4)));

struct U2 { unsigned x, y; };

__device__ __forceinline__ unsigned short f2bf(float f) {
    union { float f; unsigned u; } v; v.f = f;
    unsigned r = v.u + 0x7FFF + ((v.u >> 16) & 1);   // RNE
    return (unsigned short)(r >> 16);
}

__device__ __forceinline__ float bf2f(unsigned short u) {
    union { unsigned u; float f; } v; v.u = ((unsigned)u) << 16;
    return v.f;
}

__device__ __forceinline__ float fast_exp2(float x) {
#if __has_builtin(__builtin_amdgcn_exp2f)
    return __builtin_amdgcn_exp2f(x);
#else
    return exp2f(x);
#endif
}

// ---------------------------------------------------------------------------
// Kernel 1: projections as 3 output-groups x 2 c-halves (wave-uniform og/ch).
//   og=0: f[0:8]+g[0:8], og=1: h[0:16), og=2: h[16:32).
//   Weights via wave-uniform scalar loads; c-halves reduced through LDS.
//   f pre-scaled by log2(e).  fB,gB: [b][n][8]; hBt: [b][n/8][32][n%8] bf16.
// ---------------------------------------------------------------------------
__global__ __launch_bounds__(256) void proj_kernel(
        const float* __restrict__ x,
        const float* __restrict__ Wf, const float* __restrict__ bf,
        const float* __restrict__ Wg, const float* __restrict__ bg,
        const float* __restrict__ Wh, const float* __restrict__ bh,
        unsigned short* __restrict__ fB,
        unsigned short* __restrict__ gB,
        unsigned short* __restrict__ hBt) {
    __shared__ float red[16][128];

    const int t = threadIdx.x;
    const int px = t & 127;
    const int ch = __builtin_amdgcn_readfirstlane(t >> 7);   // wave-uniform 0/1
    const int og = blockIdx.y;                                // uniform 0..2
    const int pix = blockIdx.x * 128 + px;
    const int b = pix >> 12, n = pix & (NPIX - 1);
    const float L2E = 1.44269504088896f;

    const float* xb = x + (size_t)b * CDIM * NPIX + n + (size_t)(ch * 32) * NPIX;
    float xv[32];
#pragma unroll 8
    for (int c = 0; c < 32; c++) xv[c] = xb[(size_t)c * NPIX];

    float acc[16];

    if (og == 0) {
        const float* wf = Wf + ch * 32;
        const float* wg = Wg + ch * 32;
#pragma unroll
        for (int r = 0; r < 8; r++) {
            acc[r]     = ch ? 0.f : bf[r];
            acc[8 + r] = ch ? 0.f : bg[r];
        }
#pragma unroll 4
        for (int c = 0; c < 32; c++) {
            float v = xv[c];
#pragma unroll
            for (int r = 0; r < 8; r++) {
                acc[r]     += wf[r * CDIM + c] * v;
                acc[8 + r] += wg[r * CDIM + c] * v;
            }
        }
    } else if (og == 1) {
        const float* wh = Wh + ch * 32;
#pragma unroll
        for (int r = 0; r < 16; r++) acc[r] = ch ? 0.f : bh[r];
#pragma unroll 4
        for (int c = 0; c < 32; c++) {
            float v = xv[c];
#pragma unroll
            for (int r = 0; r < 16; r++) acc[r] += wh[r * CDIM + c] * v;
        }
    } else {
        const float* wh = Wh + 16 * CDIM + ch * 32;
#pragma unroll
        for (int r = 0; r < 16; r++) acc[r] = ch ? 0.f : bh[16 + r];
#pragma unroll 4
        for (int c = 0; c < 32; c++) {
            float v = xv[c];
#pragma unroll
            for (int r = 0; r < 16; r++) acc[r] += wh[r * CDIM + c] * v;
        }
    }

    if (ch) {
#pragma unroll
        for (int r = 0; r < 16; r++) red[r][px] = acc[r];
    }
    __syncthreads();
    if (!ch) {
#pragma unroll
        for (int r = 0; r < 16; r++) acc[r] += red[r][px];

        unsigned short* ho = hBt + ((size_t)b * (NPIX / 8) + (n >> 3)) * (CHDIM * 8) + (n & 7);
        if (og == 0) {
            unsigned short* fo = fB + (size_t)pix * KDIM;
            unsigned short* go = gB + (size_t)pix * KDIM;
#pragma unroll
            for (int r = 0; r < 8; r++) {
                fo[r] = f2bf(acc[r] * L2E);      // fold log2(e) into f
                go[r] = f2bf(acc[8 + r]);
            }
        } else if (og == 1) {
#pragma unroll
            for (int r = 0; r < 16; r++) ho[r * 8] = f2bf(acc[r]);
        } else {
#pragma unroll
            for (int r = 0; r < 16; r++) ho[(16 + r) * 8] = f2bf(acc[r]);
        }
    }
}

// ---------------------------------------------------------------------------
// Kernel 2: flash attention, j-split, no max-tracking, j-loop unrolled x2
// with immediate-offset loads and double-buffered P-LDS.
//   S^T = mfma(g, f) -> p = exp2(st) -> cvt_pk -> padded-LDS roundtrip
//   -> O^T += mfma(h, P);  bf16 partial acc + fp32 partial l to ws.
// ---------------------------------------------------------------------------
__global__ __launch_bounds__(256) void attn_kernel(
        const unsigned short* __restrict__ fB,
        const unsigned short* __restrict__ gB,
        const unsigned short* __restrict__ hBt,
        unsigned short* __restrict__ oTp, float* __restrict__ lp, int jlen) {
    __shared__ unsigned short plds[8][16][40];   // [wave*2+buf], padded 80B rows

    const int wid = threadIdx.x >> 6;
    const int lane = threadIdx.x & 63;
    const int li = lane & 15;
    const int q = lane >> 4;
    const int b = blockIdx.y;
    const int split = blockIdx.z;
    const int i0 = blockIdx.x * 64 + wid * 16;
    const int j0 = split * jlen;

    bf16x8 ffrag = {};
    if (lane < 16)
        ffrag = *(const bf16x8*)(fB + ((size_t)b * NPIX + i0 + lane) * KDIM);

    f32x4 acc0 = {0.f, 0.f, 0.f, 0.f};
    f32x4 acc1 = {0.f, 0.f, 0.f, 0.f};
    float lsum = 0.f;
    const f32x4 z = {0.f, 0.f, 0.f, 0.f};

    const unsigned short* gb = gB + ((size_t)b * NPIX + j0 + lane) * KDIM;
    const unsigned short* hb = hBt + ((size_t)b * (NPIX / 8) + (j0 >> 3) + q) * (CHDIM * 8) + li * 8;

#define ATTN_STEP(G0, G1, H0, H1, BUF)                                          \
    {                                                                           \
        f32x4 st0 = __builtin_amdgcn_mfma_f32_16x16x32_bf16(G0, ffrag, z, 0, 0, 0); \
        f32x4 st1 = __builtin_amdgcn_mfma_f32_16x16x32_bf16(G1, ffrag, z, 0, 0, 0); \
        float p0 = fast_exp2(st0[0]), p1 = fast_exp2(st0[1]);                   \
        float p2 = fast_exp2(st0[2]), p3 = fast_exp2(st0[3]);                   \
        float p4 = fast_exp2(st1[0]), p5 = fast_exp2(st1[1]);                   \
        float p6 = fast_exp2(st1[2]), p7 = fast_exp2(st1[3]);                   \
        lsum += ((p0 + p1) + (p2 + p3)) + ((p4 + p5) + (p6 + p7));              \
        unsigned u01, u23, u45, u67;                                            \
        asm("v_cvt_pk_bf16_f32 %0, %1, %2" : "=v"(u01) : "v"(p0), "v"(p1));     \
        asm("v_cvt_pk_bf16_f32 %0, %1, %2" : "=v"(u23) : "v"(p2), "v"(p3));     \
        asm("v_cvt_pk_bf16_f32 %0, %1, %2" : "=v"(u45) : "v"(p4), "v"(p5));     \
        asm("v_cvt_pk_bf16_f32 %0, %1, %2" : "=v"(u67) : "v"(p6), "v"(p7));     \
        *(U2*)&plds[BUF][li][4 * q]      = U2{u01, u23};                        \
        *(U2*)&plds[BUF][li][16 + 4 * q] = U2{u45, u67};                        \
        bf16x8 pfrag = *(const bf16x8*)&plds[BUF][li][8 * q];                   \
        acc0 = __builtin_amdgcn_mfma_f32_16x16x32_bf16(H0, pfrag, acc0, 0, 0, 0); \
        acc1 = __builtin_amdgcn_mfma_f32_16x16x32_bf16(H1, pfrag, acc1, 0, 0, 0); \
    }

    for (int jb = 0; jb < jlen; jb += 64) {
        bf16x8 g0 = {}, g1 = {}, g2 = {}, g3 = {};
        if (lane < 16) {
            g0 = *(const bf16x8*)(gb);                 // +0
            g1 = *(const bf16x8*)(gb + 16 * KDIM);     // +256B
            g2 = *(const bf16x8*)(gb + 32 * KDIM);     // +512B
            g3 = *(const bf16x8*)(gb + 48 * KDIM);     // +768B
        }
        bf16x8 h0 = *(const bf16x8*)(hb);              // +0
        bf16x8 h1 = *(const bf16x8*)(hb + 128);        // +256B
        bf16x8 h2 = *(const bf16x8*)(hb + 1024);       // +2048B
        bf16x8 h3 = *(const bf16x8*)(hb + 1152);       // +2304B

        ATTN_STEP(g0, g1, h0, h1, wid * 2)
        ATTN_STEP(g2, g3, h2, h3, wid * 2 + 1)

        gb += 64 * KDIM;
        hb += 8 * CHDIM * 8;
    }
#undef ATTN_STEP

    lsum += __shfl_xor(lsum, 16);
    lsum += __shfl_xor(lsum, 32);

    unsigned short* ob = oTp + ((size_t)(split * BATCH + b) * CHDIM) * NPIX + (i0 + li);
#pragma unroll
    for (int r = 0; r < 4; r++) {
        int c0 = q * 4 + r;
        ob[(size_t)c0 * NPIX]        = f2bf(acc0[r]);
        ob[(size_t)(16 + c0) * NPIX] = f2bf(acc1[r]);
    }
    if (lane < 16)
        lp[(size_t)(split * BATCH + b) * NPIX + i0 + lane] = lsum;
}

// ---------------------------------------------------------------------------
// Kernel 3: merge bf16 splits (vectorized ushort4 reads) + Wv + residual.
// ---------------------------------------------------------------------------
__global__ __launch_bounds__(256) void out_kernel(
        const unsigned short* __restrict__ oTp, const float* __restrict__ lp,
        const float* __restrict__ x,
        const float* __restrict__ Wv, const float* __restrict__ bv,
        const float* __restrict__ gamma, float* __restrict__ out, int nsplit) {
    __shared__ float otile[CHDIM * 64];
    __shared__ float linv[64];

    const int t = threadIdx.x;
    const int n0 = blockIdx.x * 64, b = blockIdx.y;

    // merge: thread reads 4 consecutive pixels of channel (t>>4)+16r, 8B/lane
    const int px4 = (t & 15) * 4;
    const int ch0 = t >> 4;          // 0..15
    float racc[2][4] = {{0.f, 0.f, 0.f, 0.f}, {0.f, 0.f, 0.f, 0.f}};
    for (int s = 0; s < nsplit; s++) {
        const unsigned short* base = oTp + ((size_t)(s * BATCH + b) * CHDIM) * NPIX + n0 + px4;
#pragma unroll
        for (int r = 0; r < 2; r++) {
            ushort4v v = *(const ushort4v*)(base + (size_t)(ch0 + r * 16) * NPIX);
#pragma unroll
            for (int k = 0; k < 4; k++) racc[r][k] += bf2f(v[k]);
        }
    }
#pragma unroll
    for (int r = 0; r < 2; r++)
#pragma unroll
        for (int k = 0; k < 4; k++)
            otile[(ch0 + r * 16) * 64 + px4 + k] = racc[r][k];

    if (t < 64) {
        float ls = 0.f;
        for (int s = 0; s < nsplit; s++)
            ls += lp[(size_t)(s * BATCH + b) * NPIX + n0 + t];
        linv[t] = 1.0f / ls;
    }
    __syncthreads();

    const int px = t & 63;
    const int cq = __builtin_amdgcn_readfirstlane(t >> 6);   // wave-uniform
    float ov[CHDIM];
#pragma unroll
    for (int chh = 0; chh < CHDIM; chh++) ov[chh] = otile[chh * 64 + px];
    float invl = linv[px];
    float gm = gamma[0];

    const float* wq = Wv + cq * 16 * CHDIM;
#pragma unroll 4
    for (int cc = 0; cc < 16; cc++) {
        float a = 0.f;
#pragma unroll
        for (int chh = 0; chh < CHDIM; chh++) a += wq[cc * CHDIM + chh] * ov[chh];
        int c = cq * 16 + cc;
        size_t o = ((size_t)b * CDIM + c) * NPIX + n0 + px;
        out[o] = gm * (a * invl + bv[c]) + x[o];
    }
}

extern "C" void kernel_launch(void* const* d_in, const int* in_sizes, int n_in,
                              void* d_out, int out_size, void* d_ws, size_t ws_size,
                              hipStream_t stream) {
    const float* x     = (const float*)d_in[0];
    const float* Wf    = (const float*)d_in[1];
    const float* bf    = (const float*)d_in[2];
    const float* Wg    = (const float*)d_in[3];
    const float* bg    = (const float*)d_in[4];
    const float* Wh    = (const float*)d_in[5];
    const float* bh    = (const float*)d_in[6];
    const float* Wv    = (const float*)d_in[7];
    const float* bv    = (const float*)d_in[8];
    const float* gamma = (const float*)d_in[9];
    float* out = (float*)d_out;

    unsigned short* fBp = (unsigned short*)d_ws;                    // 4*4096*8 bf16
    unsigned short* gBp = fBp + (size_t)BATCH * NPIX * KDIM;        // 4*4096*8
    unsigned short* hBt = gBp + (size_t)BATCH * NPIX * KDIM;        // 4*4096*32
    unsigned short* oTp = hBt + (size_t)BATCH * NPIX * CHDIM;       // nsplit*4*32*4096 bf16

    size_t fixedB   = (size_t)BATCH * NPIX * (KDIM * 2 * 2 + CHDIM * 2);
    size_t perSplit = (size_t)BATCH * CHDIM * NPIX * 2 + (size_t)BATCH * NPIX * 4;
    int nsplit = 1;
    while (nsplit < 8 && fixedB + (size_t)(nsplit * 2) * perSplit <= ws_size) nsplit *= 2;
    int jlen = NPIX / nsplit;   // >= 512, multiple of 64

    float* lp = (float*)(oTp + (size_t)nsplit * BATCH * CHDIM * NPIX);

    hipLaunchKernelGGL(proj_kernel, dim3(NPIX * BATCH / 128, 3), dim3(256), 0, stream,
                       x, Wf, bf, Wg, bg, Wh, bh, fBp, gBp, hBt);
    hipLaunchKernelGGL(attn_kernel, dim3(NPIX / 64, BATCH, nsplit), dim3(256), 0, stream,
                       fBp, gBp, hBt, oTp, lp, jlen);
    hipLaunchKernelGGL(out_kernel, dim3(NPIX / 64, BATCH), dim3(256), 0, stream,
                       oTp, lp, x, Wv, bv, gamma, out, nsplit);
}